// Round 1
// baseline (271.284 us; speedup 1.0000x reference)
//
#include <hip/hip_runtime.h>

// MRGCO: real-FFT tensor-product RGCN layer.
// Reference = real(ifft( [real(fft(A))·real(fft(X))] per-k )) then same with weight.
// cos-transform matrix has rank 5 -> only j=0..4 distinct; ifft/fft round-trip
// between the two products cancels exactly (real symmetric spectrum).
//
// Pipeline: k_xf (Xf bf16, transposed [j][h][m]) ; k_wf (Wf bf16, scaled, [j][h][h']) ;
// k_af (Af bf16 [j][n][m]) ; gemm5<bf16> C1=Af@Xf ; gemm5<float> C2=C1@Wf ; k_combine.
// Workspace: Af 40MB + Xft 5MB + Wft 0.6MB + C1 5MB + C2 10MB = 63.6MB.

typedef __bf16 bf16_t;
typedef __bf16 bf16x8 __attribute__((ext_vector_type(8)));
typedef float f32x4 __attribute__((ext_vector_type(4)));

#define R2C 0.70710678118654752f

__device__ __forceinline__ void fwd5(const float x[8], float F[5]) {
  float s04 = x[0] + x[4], d04 = x[0] - x[4];
  float s26 = x[2] + x[6];
  float s15 = x[1] + x[5], s37 = x[3] + x[7];
  float t = (x[1] + x[7]) - (x[3] + x[5]);
  float e = s04 + s26, o = s15 + s37;
  F[0] = e + o;
  F[1] = d04 + R2C * t;
  F[2] = s04 - s26;
  F[3] = d04 - R2C * t;
  F[4] = e - o;
}

// Xft[j][h][m] = sum_k X[m][h][k] c_jk   (B-operand of GEMM1, K(m)-contiguous)
__global__ __launch_bounds__(256) void k_xf(const float* __restrict__ X,
                                            bf16_t* __restrict__ Xft) {
  int m = blockIdx.x * 256 + threadIdx.x;
  int h = blockIdx.y;
  const float4* p = (const float4*)(X + ((size_t)m * 256 + h) * 8);
  float4 a = p[0], b = p[1];
  float x[8] = {a.x, a.y, a.z, a.w, b.x, b.y, b.z, b.w};
  float F[5];
  fwd5(x, F);
  size_t base = (size_t)h * 2048 + m;
#pragma unroll
  for (int j = 0; j < 5; j++) Xft[(size_t)j * 524288 + base] = (bf16_t)F[j];
}

// Wft[j][h][h'] = s_j * sum_k W[h'][h][k] c_jk  (B-operand of GEMM2)
__global__ __launch_bounds__(256) void k_wf(const float* __restrict__ W,
                                            bf16_t* __restrict__ Wft) {
  int hp = threadIdx.x;   // h' = contraction dim
  int h = blockIdx.y;
  const float4* p = (const float4*)(W + ((size_t)hp * 256 + h) * 8);
  float4 a = p[0], b = p[1];
  float x[8] = {a.x, a.y, a.z, a.w, b.x, b.y, b.z, b.w};
  float F[5];
  fwd5(x, F);
  const float sc[5] = {0.125f, 0.25f, 0.25f, 0.25f, 0.125f};
  size_t base = (size_t)h * 256 + hp;
#pragma unroll
  for (int j = 0; j < 5; j++) Wft[(size_t)j * 65536 + base] = (bf16_t)(F[j] * sc[j]);
}

// Af[j][n][m] = sum_k A[n][m][k] c_jk
__global__ __launch_bounds__(256) void k_af(const float* __restrict__ A,
                                            bf16_t* __restrict__ Af) {
  size_t idx = (size_t)blockIdx.x * 256 + threadIdx.x;  // n*2048 + m
  const float4* p = (const float4*)(A + idx * 8);
  float4 a = p[0], b = p[1];
  float x[8] = {a.x, a.y, a.z, a.w, b.x, b.y, b.z, b.w};
  float F[5];
  fwd5(x, F);
#pragma unroll
  for (int j = 0; j < 5; j++) Af[(size_t)j * 4194304 + idx] = (bf16_t)F[j];
}

// Batched (z=j) bf16 GEMM: C[n][h] = sum_k A[n][k]*B[h][k].  M=2048 (grid.x*128),
// N=256 (grid.y*128), K param. Both operands K-contiguous rows. 128x128 tile,
// BK=64, 4 waves each 64x64, 16x16x32 MFMA. XOR-swizzled LDS (16B chunks).
template <typename OutT>
__global__ __launch_bounds__(256) void gemm5(const bf16_t* __restrict__ A,
                                             const bf16_t* __restrict__ B,
                                             OutT* __restrict__ C, int K,
                                             size_t ap, size_t bp, size_t cp) {
  constexpr int BK = 64;
  __shared__ bf16_t As[128 * BK];
  __shared__ bf16_t Bs[128 * BK];
  const int j = blockIdx.z;
  const bf16_t* Aj = A + (size_t)j * ap;
  const bf16_t* Bj = B + (size_t)j * bp;
  OutT* Cj = C + (size_t)j * cp;
  const int n0 = blockIdx.x * 128, h0 = blockIdx.y * 128;
  const int tid = threadIdx.x;
  const int wv = tid >> 6, ln = tid & 63;
  const int quad = ln >> 4, l16 = ln & 15;
  const int wn = (wv & 1) * 64, wh = (wv >> 1) * 64;
  f32x4 acc[4][4] = {};

  for (int kk = 0; kk < K; kk += BK) {
    __syncthreads();
#pragma unroll
    for (int s = 0; s < 4; s++) {
      int slot = tid + s * 256;  // 0..1023 16B-chunks per 16KB tile
      int row = slot >> 3;       // 128B (64 elem) per row
      int c16 = slot & 7;
      int dst = row * 64 + (((c16) ^ (row & 7)) << 3);
      size_t goff = (size_t)kk + c16 * 8;
      uint4 va = *(const uint4*)(Aj + (size_t)(n0 + row) * K + goff);
      uint4 vb = *(const uint4*)(Bj + (size_t)(h0 + row) * K + goff);
      *(uint4*)(As + dst) = va;
      *(uint4*)(Bs + dst) = vb;
    }
    __syncthreads();
#pragma unroll
    for (int kh = 0; kh < 2; kh++) {
      bf16x8 af[4], bfr[4];
      int c16 = kh * 4 + quad;
#pragma unroll
      for (int i = 0; i < 4; i++) {
        int ra = wn + i * 16 + l16;
        int rb = wh + i * 16 + l16;
        af[i] = *(const bf16x8*)(As + ra * 64 + ((c16 ^ (ra & 7)) << 3));
        bfr[i] = *(const bf16x8*)(Bs + rb * 64 + ((c16 ^ (rb & 7)) << 3));
      }
#pragma unroll
      for (int i = 0; i < 4; i++)
#pragma unroll
        for (int t = 0; t < 4; t++)
          acc[i][t] = __builtin_amdgcn_mfma_f32_16x16x32_bf16(af[i], bfr[t],
                                                              acc[i][t], 0, 0, 0);
    }
  }
  // C/D layout: col = lane&15, row = quad*4 + reg (m89/m91-verified)
#pragma unroll
  for (int i = 0; i < 4; i++) {
#pragma unroll
    for (int t = 0; t < 4; t++) {
      int hc = h0 + wh + t * 16 + l16;
#pragma unroll
      for (int rg = 0; rg < 4; rg++) {
        int nr = n0 + wn + i * 16 + quad * 4 + rg;
        Cj[(size_t)nr * 256 + hc] = (OutT)acc[i][t][rg];
      }
    }
  }
}

// out[n][h][k] = sum_{j=0..4} c_jk * C2_j[n][h]  (scales already folded into Wf)
__global__ __launch_bounds__(256) void k_combine(const float* __restrict__ C2,
                                                 float* __restrict__ out) {
  size_t idx = (size_t)blockIdx.x * 256 + threadIdx.x;  // n*256+h
  float c0 = C2[idx];
  float c1 = C2[524288 + idx];
  float c2 = C2[2 * 524288 + idx];
  float c3 = C2[3 * 524288 + idx];
  float c4 = C2[4 * 524288 + idx];
  float o0 = c0 + c1 + c2 + c3 + c4;
  float o4 = c0 - c1 + c2 - c3 + c4;
  float o2 = c0 - c2 + c4;
  float rt = R2C * (c1 - c3);
  float o1 = c0 + rt - c4;
  float o3 = c0 - rt - c4;
  float4* op = (float4*)(out + idx * 8);
  op[0] = make_float4(o0, o1, o2, o3);
  op[1] = make_float4(o4, o3, o2, o1);
}

extern "C" void kernel_launch(void* const* d_in, const int* in_sizes, int n_in,
                              void* d_out, int out_size, void* d_ws, size_t ws_size,
                              hipStream_t stream) {
  const float* X = (const float*)d_in[0];   // (2048,256,8)
  const float* A = (const float*)d_in[1];   // (2048,2048,8)
  const float* W = (const float*)d_in[2];   // (256,256,8)
  float* out = (float*)d_out;               // (2048,256,8)
  char* ws = (char*)d_ws;

  bf16_t* Af  = (bf16_t*)(ws);              // 5*2048*2048*2 = 41943040
  bf16_t* Xft = (bf16_t*)(ws + 41943040);   // 5*256*2048*2  =  5242880
  bf16_t* Wft = (bf16_t*)(ws + 47185920);   // 5*256*256*2   =   655360
  bf16_t* C1  = (bf16_t*)(ws + 47841280);   // 5*2048*256*2  =  5242880
  float*  C2  = (float*) (ws + 53084160);   // 5*2048*256*4  = 10485760
                                            // total 63569920 B

  k_xf<<<dim3(8, 256), 256, 0, stream>>>(X, Xft);
  k_wf<<<dim3(1, 256), 256, 0, stream>>>(W, Wft);
  k_af<<<dim3(16384), 256, 0, stream>>>(A, Af);
  gemm5<bf16_t><<<dim3(16, 2, 5), 256, 0, stream>>>(Af, Xft, C1, 2048,
                                                    (size_t)4194304, (size_t)524288,
                                                    (size_t)524288);
  gemm5<float><<<dim3(16, 2, 5), 256, 0, stream>>>(C1, Wft, C2, 256,
                                                   (size_t)524288, (size_t)65536,
                                                   (size_t)524288);
  k_combine<<<dim3(2048), 256, 0, stream>>>(C2, out);
}